// Round 9
// baseline (240.732 us; speedup 1.0000x reference)
//
#include <hip/hip_runtime.h>

typedef float f16v __attribute__((ext_vector_type(16)));
typedef float f4 __attribute__((ext_vector_type(4)));
typedef float f2 __attribute__((ext_vector_type(2)));

// static_for with FRONTEND-constant indices: vector subscripts lower to
// constant-index insert/extractelement (SSA, no alloca). #pragma unroll loop
// vars are not frontend-constant -> variable GEP -> alloca -> scratch traffic
// (R1-R5's GBs of FETCH/WRITE; R6/R7 fixed it with this).
template<int I> struct ic { static constexpr int v = I; };
template<int... I> struct iseq {};
template<int N, int... I> struct mk : mk<N-1, N-1, I...> {};
template<int... I> struct mk<0, I...> { using t = iseq<I...>; };
template<class F, int... I>
__device__ __forceinline__ void sfor_impl(F f, iseq<I...>) { (f(ic<I>{}), ...); }
template<int N, class F>
__device__ __forceinline__ void sfor(F f) { sfor_impl(f, typename mk<N>::t{}); }

namespace {
constexpr float kSigma  = 1.2f;    // 2*l2_reg + rho
constexpr float kJitter = 1e-5f;
constexpr int   kIters  = 100;
constexpr int   MD = 16;     // constraint rows
constexpr int   ND = 32;     // variables
constexpr int   SPB = 8;     // samples per block in precompute (32 lanes each)
constexpr int   SPB3 = 32;   // samples per block in iter kernel (8 lanes each)
constexpr int   AS  = 132;   // A sample stride in float4 (528 floats; 528%32==16)
constexpr int   SS  = 36;    // s-slot stride in floats
constexpr int   MIS = 20;    // Minv row stride in floats (80B: b128-aligned, 2-way banks)
}

// A tile in LDS: per sample 16 rows x 8 float4, f4 index xor-swizzled with row.
__device__ __forceinline__ float4 lds_a4(const float* As, int r, int j) {
    return *reinterpret_cast<const float4*>(&As[r * 32 + ((j ^ (r & 7)) << 2)]);
}
__device__ __forceinline__ float lds_a(const float* As, int r, int n) {
    return As[r * 32 + ((((n >> 2) ^ (r & 7)) << 2) | (n & 3))];
}

// ============================ Kernel A: precompute P, d ============================
// P stored COLUMN-MAJOR per sample: Pws[gs*1024 + n*32 + row] = P[row][n].
// Lane l (row l) stores 32 scalars; per column n the 32 lanes write 128B coalesced.
// Kernel B lane l3 then loads f4 = rows (4l3..4l3+3) of column n, coalesced.
__global__ void __launch_bounds__(256)
precompute_kernel(const float* __restrict__ Ag, const float* __restrict__ bg,
                  const float* __restrict__ cg, float* __restrict__ Pws,
                  float* __restrict__ dws)
{
    __shared__ __align__(16) float A_lds[SPB * AS * 4];       // 16896 B
    __shared__ __align__(16) float Minv_lds[SPB * MD * MIS];  // 10240 B

    const int t = threadIdx.x;

    // ---- stage A for the block's 8 samples (coalesced, xor-swizzled f4)
    {
        const float4* src = reinterpret_cast<const float4*>(Ag) +
                            (size_t)blockIdx.x * (SPB * MD * ND / 4);
        float4* dst = reinterpret_cast<float4*>(A_lds);
        #pragma unroll
        for (int r = 0; r < 4; ++r) {
            int idx = r * 256 + t;
            int smp = idx >> 7;
            int row = (idx >> 3) & 15;
            int j   = idx & 7;
            dst[smp * AS + row * 8 + (j ^ (row & 7))] = src[idx];
        }
    }
    __syncthreads();

    const int lane = t & 63;
    const int l    = lane & 31;
    const int lr   = l & 15;
    const int smp  = (t >> 6) * 2 + (lane >> 5);
    const size_t gs = (size_t)blockIdx.x * SPB + smp;
    const float* As = &A_lds[smp * AS * 4];
    float* Mi = &Minv_lds[smp * MD * MIS];

    // ---- M = A A^T + jitter*I (row lr); operand rows from LDS (va CSE'd by compiler)
    f16v Mrow, Vrow;
    sfor<16>([&](auto K) {
        constexpr int k = decltype(K)::v;
        float a0 = 0.f, a1 = 0.f, a2 = 0.f, a3 = 0.f;
        sfor<8>([&](auto J) {
            constexpr int j = decltype(J)::v;
            float4 va = lds_a4(As, lr, j);
            float4 vb = lds_a4(As, k, j);
            a0 += va.x*vb.x; a1 += va.y*vb.y; a2 += va.z*vb.z; a3 += va.w*vb.w;
        });
        Mrow[k] = (a0+a1)+(a2+a3) + ((k == lr) ? kJitter : 0.f);
        Vrow[k] = (k == lr) ? 1.f : 0.f;
    });

    // ---- TRIANGULAR Gauss-Jordan inverse (SPD -> no pivoting), width-32 shuffles.
    // At step k: M cols j<k are e_j (skip), col k post-value never re-read (skip);
    // V cols j>k still e_j (skip); V col k closed-form: V[k][k]=1, V[r!=k][k]=0
    // before the step -> V'[r][k] = (r==k) ? ip : -f. Shuffles: 528 -> 256.
    sfor<16>([&](auto K) {
        constexpr int k = decltype(K)::v;
        float ip = 1.f / __shfl(Mrow[k], k, 32);
        float f  = (lr == k) ? 0.f : Mrow[k] * ip;
        sfor<16>([&](auto J) {
            constexpr int j = decltype(J)::v;
            if constexpr (j > k) {
                float mj = __shfl(Mrow[j], k, 32);
                Mrow[j] = (lr == k) ? mj * ip : Mrow[j] - f * mj;
            }
        });
        sfor<16>([&](auto J) {
            constexpr int j = decltype(J)::v;
            if constexpr (j < k) {
                float vj = __shfl(Vrow[j], k, 32);
                Vrow[j] = (lr == k) ? vj * ip : Vrow[j] - f * vj;
            }
        });
        Vrow[k] = (lr == k) ? ip : -f;
    });

    // ---- w = Minv b while Vrow is live (lane holds w[lr], dup in upper half)
    float w = 0.f;
    {
        float bval = bg[gs * MD + lr];
        sfor<16>([&](auto K) {
            constexpr int k = decltype(K)::v;
            w += Vrow[k] * __shfl(bval, k, 32);
        });
    }

    // ---- hand Minv to LDS (row lr); Vrow dead after. Same-wave producers/consumers.
    if (l < 16) {
        sfor<4>([&](auto J) {
            constexpr int j = decltype(J)::v;
            *reinterpret_cast<float4*>(&Mi[lr * MIS + 4*j]) =
                make_float4(Vrow[4*j+0], Vrow[4*j+1], Vrow[4*j+2], Vrow[4*j+3]);
        });
    }
    asm volatile("s_waitcnt lgkmcnt(0)" ::: "memory");

    // ---- C row l of A^T Minv: C[m] = sum_k A[k][l] * Minv[k][m] (Minv uniform b128)
    f16v C = (f16v)0.0f;
    sfor<16>([&](auto K) {
        constexpr int k = decltype(K)::v;
        float a = lds_a(As, k, l);
        sfor<4>([&](auto J) {
            constexpr int j = decltype(J)::v;
            float4 mv = *reinterpret_cast<const float4*>(&Mi[k * MIS + 4*j]);
            C[4*j+0] += a * mv.x; C[4*j+1] += a * mv.y;
            C[4*j+2] += a * mv.z; C[4*j+3] += a * mv.w;
        });
    });

    // ---- P row l = (I - C A)/sigma: Pa[n]=P[l][n], Pb[n]=P[l][n+16]
    f16v Pa = (f16v)0.0f, Pb = (f16v)0.0f;
    sfor<16>([&](auto M) {
        constexpr int m = decltype(M)::v;
        float cm = C[m];
        sfor<4>([&](auto J) {
            constexpr int j = decltype(J)::v;
            float4 v  = lds_a4(As, m, j);
            Pa[4*j+0] += cm*v.x;  Pa[4*j+1] += cm*v.y;
            Pa[4*j+2] += cm*v.z;  Pa[4*j+3] += cm*v.w;
            float4 w4 = lds_a4(As, m, j + 4);
            Pb[4*j+0] += cm*w4.x; Pb[4*j+1] += cm*w4.y;
            Pb[4*j+2] += cm*w4.z; Pb[4*j+3] += cm*w4.w;
        });
    });
    constexpr float is = 1.f / kSigma;
    sfor<16>([&](auto N) {
        constexpr int n = decltype(N)::v;
        Pa[n] = (((n      == l) ? 1.f : 0.f) - Pa[n]) * is;
        Pb[n] = (((n + 16 == l) ? 1.f : 0.f) - Pb[n]) * is;
    });

    // ---- d = A^T w - P c
    float d;
    {
        float q = 0.f;
        sfor<16>([&](auto M) {
            constexpr int m = decltype(M)::v;
            q += lds_a(As, m, l) * __shfl(w, m, 32);
        });
        float cval = cg[gs * ND + l];
        float pc0 = 0.f, pc1 = 0.f;
        sfor<16>([&](auto N) {
            constexpr int n = decltype(N)::v;
            pc0 += Pa[n] * __shfl(cval, n,      32);
            pc1 += Pb[n] * __shfl(cval, n + 16, 32);
        });
        d = q - (pc0 + pc1);
    }

    // ---- store P column-major (coalesced per column), and d
    {
        float* Pout = Pws + gs * (ND * ND);
        sfor<16>([&](auto N) {
            constexpr int n = decltype(N)::v;
            Pout[n * 32 + l]        = Pa[n];
            Pout[(n + 16) * 32 + l] = Pb[n];
        });
    }
    dws[gs * ND + l] = d;
}

// ============================ Kernel B: 100 ADMM iterations ============================
// 8 lanes/sample, 4 variables/lane (P rows 4l3..4l3+3 as 32 column-f4s in regs).
// Per wave: 1 f4 write + 8 b128 uniform reads serve EIGHT samples (DS/sample 2x down).
__global__ void __launch_bounds__(256)
admm_iter_kernel(const float* __restrict__ Pws, const float* __restrict__ dws,
                 const float* __restrict__ lbg, const float* __restrict__ ubg,
                 float* __restrict__ outg)
{
    __shared__ __align__(16) float S_lds[SPB3 * SS];   // 4608 B

    const int t = threadIdx.x;
    const int lane = t & 63;
    const int l3 = lane & 7;                       // lane within 8-lane group
    const int smp = (t >> 6) * 8 + (lane >> 3);    // sample within block
    const size_t gs = (size_t)blockIdx.x * SPB3 + smp;
    float* Sb = &S_lds[smp * SS];

    // p{n} = column n of P for this lane's 4 rows; coalesced f4 loads
    const f4* Pw = reinterpret_cast<const f4*>(Pws + gs * (ND * ND));
#define PLOAD(n) f4 p##n = Pw[n * 8 + l3];
    PLOAD(0)  PLOAD(1)  PLOAD(2)  PLOAD(3)  PLOAD(4)  PLOAD(5)  PLOAD(6)  PLOAD(7)
    PLOAD(8)  PLOAD(9)  PLOAD(10) PLOAD(11) PLOAD(12) PLOAD(13) PLOAD(14) PLOAD(15)
    PLOAD(16) PLOAD(17) PLOAD(18) PLOAD(19) PLOAD(20) PLOAD(21) PLOAD(22) PLOAD(23)
    PLOAD(24) PLOAD(25) PLOAD(26) PLOAD(27) PLOAD(28) PLOAD(29) PLOAD(30) PLOAD(31)
#undef PLOAD

    f4 dv = *reinterpret_cast<const f4*>(dws + gs * ND + 4 * l3);
    f4 lb = *reinterpret_cast<const f4*>(lbg + gs * ND + 4 * l3);
    f4 ub = *reinterpret_cast<const f4*>(ubg + gs * ND + 4 * l3);
    f4 z  = __builtin_elementwise_min(__builtin_elementwise_max((f4)0.0f, lb), ub);
    f4 u  = (f4)0.0f;
    f4 x  = (f4)0.0f;

    const f4* Sv = reinterpret_cast<const f4*>(Sb);
    for (int it = 0; it < kIters; ++it) {
        *reinterpret_cast<f4*>(&Sb[4 * l3]) = z - u;       // rho == 1
        asm volatile("s_waitcnt lgkmcnt(0)" ::: "memory"); // wave-synchronous exchange
        f4 acc0 = dv;
        f4 acc1 = (f4)0.0f, acc2 = (f4)0.0f, acc3 = (f4)0.0f;
#define QSTEP(q, pa, pb, pc, pd)                                              \
        {                                                                     \
            f4 S4 = Sv[q];            /* uniform per 8-lane group */          \
            acc0 = __builtin_elementwise_fma(pa, __builtin_shufflevector(S4,S4,0,0,0,0), acc0); \
            acc1 = __builtin_elementwise_fma(pb, __builtin_shufflevector(S4,S4,1,1,1,1), acc1); \
            acc2 = __builtin_elementwise_fma(pc, __builtin_shufflevector(S4,S4,2,2,2,2), acc2); \
            acc3 = __builtin_elementwise_fma(pd, __builtin_shufflevector(S4,S4,3,3,3,3), acc3); \
        }
        QSTEP(0, p0,  p1,  p2,  p3)   QSTEP(1, p4,  p5,  p6,  p7)
        QSTEP(2, p8,  p9,  p10, p11)  QSTEP(3, p12, p13, p14, p15)
        QSTEP(4, p16, p17, p18, p19)  QSTEP(5, p20, p21, p22, p23)
        QSTEP(6, p24, p25, p26, p27)  QSTEP(7, p28, p29, p30, p31)
#undef QSTEP
        x = (acc0 + acc1) + (acc2 + acc3);
        f4 tv = x + u;
        z = __builtin_elementwise_min(__builtin_elementwise_max(tv, lb), ub);
        u = tv - z;
    }

    *reinterpret_cast<f4*>(outg + gs * ND + 4 * l3) = x;
}

// ==================== Fallback: R6 single kernel (if ws too small) ====================
__global__ void __launch_bounds__(256)
admm_qp_kernel(const float* __restrict__ Ag, const float* __restrict__ bg,
               const float* __restrict__ cg, const float* __restrict__ lbg,
               const float* __restrict__ ubg, float* __restrict__ outg)
{
    __shared__ __align__(16) float A_lds[SPB * AS * 4];
    __shared__ __align__(16) float S_lds[SPB * SS];

    const int t = threadIdx.x;
    {
        const float4* src = reinterpret_cast<const float4*>(Ag) +
                            (size_t)blockIdx.x * (SPB * MD * ND / 4);
        float4* dst = reinterpret_cast<float4*>(A_lds);
        #pragma unroll
        for (int r = 0; r < 4; ++r) {
            int idx = r * 256 + t;
            int smp = idx >> 7;
            int row = (idx >> 3) & 15;
            int j   = idx & 7;
            dst[smp * AS + row * 8 + (j ^ (row & 7))] = src[idx];
        }
    }
    __syncthreads();

    const int lane = t & 63;
    const int l    = lane & 31;
    const int lr   = l & 15;
    const int smp  = (t >> 6) * 2 + (lane >> 5);
    const size_t gs = (size_t)blockIdx.x * SPB + smp;
    const float* As = &A_lds[smp * AS * 4];
    float* Sb = &S_lds[smp * SS];

    f16v Mrow, Vrow;
    sfor<16>([&](auto K) {
        constexpr int k = decltype(K)::v;
        float a0 = 0.f, a1 = 0.f, a2 = 0.f, a3 = 0.f;
        sfor<8>([&](auto J) {
            constexpr int j = decltype(J)::v;
            float4 va = lds_a4(As, lr, j);
            float4 vb = lds_a4(As, k, j);
            a0 += va.x*vb.x; a1 += va.y*vb.y; a2 += va.z*vb.z; a3 += va.w*vb.w;
        });
        Mrow[k] = (a0+a1)+(a2+a3) + ((k == lr) ? kJitter : 0.f);
        Vrow[k] = (k == lr) ? 1.f : 0.f;
    });
    sfor<16>([&](auto K) {
        constexpr int k = decltype(K)::v;
        float ip = 1.f / __shfl(Mrow[k], k, 32);
        float f  = (lr == k) ? 0.f : Mrow[k] * ip;
        sfor<16>([&](auto J) {
            constexpr int j = decltype(J)::v;
            if constexpr (j > k) {
                float mj = __shfl(Mrow[j], k, 32);
                Mrow[j] = (lr == k) ? mj * ip : Mrow[j] - f * mj;
            }
        });
        sfor<16>([&](auto J) {
            constexpr int j = decltype(J)::v;
            if constexpr (j < k) {
                float vj = __shfl(Vrow[j], k, 32);
                Vrow[j] = (lr == k) ? vj * ip : Vrow[j] - f * vj;
            }
        });
        Vrow[k] = (lr == k) ? ip : -f;
    });
    float w = 0.f;
    {
        float bval = bg[gs * MD + lr];
        sfor<16>([&](auto K) {
            constexpr int k = decltype(K)::v;
            w += Vrow[k] * __shfl(bval, k, 32);
        });
    }
    f16v C = (f16v)0.0f;
    sfor<16>([&](auto K) {
        constexpr int k = decltype(K)::v;
        float a = lds_a(As, k, l);
        sfor<16>([&](auto M) {
            constexpr int m = decltype(M)::v;
            C[m] += a * __shfl(Vrow[m], k, 32);
        });
    });
    f16v Pa = (f16v)0.0f, Pb = (f16v)0.0f;
    sfor<16>([&](auto M) {
        constexpr int m = decltype(M)::v;
        float cm = C[m];
        sfor<4>([&](auto J) {
            constexpr int j = decltype(J)::v;
            float4 v  = lds_a4(As, m, j);
            Pa[4*j+0] += cm*v.x;  Pa[4*j+1] += cm*v.y;
            Pa[4*j+2] += cm*v.z;  Pa[4*j+3] += cm*v.w;
            float4 w4 = lds_a4(As, m, j + 4);
            Pb[4*j+0] += cm*w4.x; Pb[4*j+1] += cm*w4.y;
            Pb[4*j+2] += cm*w4.z; Pb[4*j+3] += cm*w4.w;
        });
    });
    constexpr float is = 1.f / kSigma;
    sfor<16>([&](auto N) {
        constexpr int n = decltype(N)::v;
        Pa[n] = (((n      == l) ? 1.f : 0.f) - Pa[n]) * is;
        Pb[n] = (((n + 16 == l) ? 1.f : 0.f) - Pb[n]) * is;
    });
    float d;
    {
        float q = 0.f;
        sfor<16>([&](auto M) {
            constexpr int m = decltype(M)::v;
            q += lds_a(As, m, l) * __shfl(w, m, 32);
        });
        float cval = cg[gs * ND + l];
        float pc0 = 0.f, pc1 = 0.f;
        sfor<16>([&](auto N) {
            constexpr int n = decltype(N)::v;
            pc0 += Pa[n] * __shfl(cval, n,      32);
            pc1 += Pb[n] * __shfl(cval, n + 16, 32);
        });
        d = q - (pc0 + pc1);
    }
    float lb = lbg[gs * ND + l];
    float ub = ubg[gs * ND + l];
    float z  = fminf(fmaxf(0.f, lb), ub);
    float u  = 0.f, x = 0.f;
    for (int it = 0; it < kIters; ++it) {
        Sb[l] = z - u;
        asm volatile("s_waitcnt lgkmcnt(0)" ::: "memory");
        float a0 = d, a1 = 0.f, a2 = 0.f, a3 = 0.f;
        sfor<4>([&](auto K) {
            constexpr int k = decltype(K)::v;
            float4 sA = *reinterpret_cast<const float4*>(&Sb[4*k]);
            float4 sB = *reinterpret_cast<const float4*>(&Sb[4*k + 16]);
            a0 += Pa[4*k+0]*sA.x + Pb[4*k+0]*sB.x;
            a1 += Pa[4*k+1]*sA.y + Pb[4*k+1]*sB.y;
            a2 += Pa[4*k+2]*sA.z + Pb[4*k+2]*sB.z;
            a3 += Pa[4*k+3]*sA.w + Pb[4*k+3]*sB.w;
        });
        x = (a0 + a1) + (a2 + a3);
        float tv = x + u;
        z = fminf(fmaxf(tv, lb), ub);
        u = tv - z;
    }
    outg[gs * ND + l] = x;
}

extern "C" void kernel_launch(void* const* d_in, const int* in_sizes, int n_in,
                              void* d_out, int out_size, void* d_ws, size_t ws_size,
                              hipStream_t stream) {
    const float* A  = (const float*)d_in[0];
    const float* b  = (const float*)d_in[1];
    const float* c  = (const float*)d_in[2];
    const float* lb = (const float*)d_in[3];
    const float* ub = (const float*)d_in[4];
    float* out = (float*)d_out;
    const int B = in_sizes[1] / MD;                       // 32768 samples
    const size_t needP = (size_t)B * ND * ND * sizeof(float);   // 128 MiB
    const size_t needD = (size_t)B * ND * sizeof(float);        // 4 MiB
    if (ws_size >= needP + needD) {
        float* Pws = (float*)d_ws;
        float* dws = Pws + (size_t)B * ND * ND;
        precompute_kernel<<<B / SPB, 256, 0, stream>>>(A, b, c, Pws, dws);
        admm_iter_kernel<<<B / SPB3, 256, 0, stream>>>(Pws, dws, lb, ub, out);
    } else {
        admm_qp_kernel<<<B / SPB, 256, 0, stream>>>(A, b, c, lb, ub, out);
    }
}

// Round 10
// 181.614 us; speedup vs baseline: 1.3255x; 1.3255x over previous
//
#include <hip/hip_runtime.h>

typedef float f16v __attribute__((ext_vector_type(16)));
typedef float f4 __attribute__((ext_vector_type(4)));
typedef float f2 __attribute__((ext_vector_type(2)));

// static_for with FRONTEND-constant indices: vector subscripts lower to
// constant-index insert/extractelement (SSA, no alloca). #pragma unroll loop
// vars are not frontend-constant -> variable GEP -> alloca -> scratch traffic
// (R1-R5's GBs of FETCH/WRITE; R6/R7 fixed it with this).
template<int I> struct ic { static constexpr int v = I; };
template<int... I> struct iseq {};
template<int N, int... I> struct mk : mk<N-1, N-1, I...> {};
template<int... I> struct mk<0, I...> { using t = iseq<I...>; };
template<class F, int... I>
__device__ __forceinline__ void sfor_impl(F f, iseq<I...>) { (f(ic<I>{}), ...); }
template<int N, class F>
__device__ __forceinline__ void sfor(F f) { sfor_impl(f, typename mk<N>::t{}); }

namespace {
constexpr float kSigma  = 1.2f;    // 2*l2_reg + rho
constexpr float kJitter = 1e-5f;
constexpr int   kIters  = 100;
constexpr int   MD = 16;     // constraint rows
constexpr int   ND = 32;     // variables
constexpr int   SPA  = 8;    // samples per 128-thread precompute block (16 lanes each)
constexpr int   SPB2 = 16;   // samples per 256-thread iter block (16 lanes each)
constexpr int   SPB  = 8;    // samples per block, fallback kernel
constexpr int   AS  = 132;   // A sample stride in float4 (528 floats; 528%32==16)
constexpr int   SS  = 36;    // s-slot stride in floats
constexpr int   MIS = 20;    // Minv row stride in floats (80B, b128-aligned)
constexpr int   MSS = 328;   // Minv SAMPLE stride in floats (328%32==8 -> groups on disjoint banks)
}

// A tile in LDS: per sample 16 rows x 8 float4, f4 index xor-swizzled with row.
__device__ __forceinline__ float4 lds_a4(const float* As, int r, int j) {
    return *reinterpret_cast<const float4*>(&As[r * 32 + ((j ^ (r & 7)) << 2)]);
}
__device__ __forceinline__ float lds_a(const float* As, int r, int n) {
    return As[r * 32 + ((((n >> 2) ^ (r & 7)) << 2) | (n & 3))];
}
// adjacent pair (n, n+1), n even -> same f4, 8B-aligned
__device__ __forceinline__ f2 lds_a2(const float* As, int r, int n) {
    return *reinterpret_cast<const f2*>(
        &As[r * 32 + ((((n >> 2) ^ (r & 7)) << 2) | (n & 3))]);
}

// ============================ Kernel A: precompute P, d ============================
// 16 lanes/sample (4 samples/wave): every uniform LDS broadcast serves 4 samples,
// halving DS instructions/sample vs the 32-lane layout (the measured 151us bound).
// Lane l owns M/Minv row l and P rows n0=2l, n1=2l+1.
// P stored in the iter kernel's layout: f4 at [gs*256 + N*16 + l] =
//   (P[2l][2N], P[2l][2N+1], P[2l+1][2N], P[2l+1][2N+1]),  N = 0..15.
__global__ void __launch_bounds__(128)
precompute_kernel(const float* __restrict__ Ag, const float* __restrict__ bg,
                  const float* __restrict__ cg, float* __restrict__ Pws,
                  float* __restrict__ dws)
{
    __shared__ __align__(16) float A_lds[SPA * AS * 4];   // 16896 B
    __shared__ __align__(16) float Mi_lds[SPA * MSS];     // 10496 B

    const int t = threadIdx.x;

    // ---- stage A for the block's 8 samples (coalesced, xor-swizzled f4)
    {
        const float4* src = reinterpret_cast<const float4*>(Ag) +
                            (size_t)blockIdx.x * (SPA * MD * ND / 4);
        float4* dst = reinterpret_cast<float4*>(A_lds);
        #pragma unroll
        for (int r = 0; r < 8; ++r) {               // 1024 f4 / 128 threads
            int idx = r * 128 + t;
            int smp = idx >> 7;
            int row = (idx >> 3) & 15;
            int j   = idx & 7;
            dst[smp * AS + row * 8 + (j ^ (row & 7))] = src[idx];
        }
    }
    __syncthreads();

    const int lane = t & 63;
    const int l    = lane & 15;                     // M-row owned by this lane
    const int n0   = 2 * l;                         // P-rows owned: n0, n0+1
    const int smp  = (t >> 6) * 4 + (lane >> 4);    // sample within block
    const size_t gs = (size_t)blockIdx.x * SPA + smp;
    const float* As = &A_lds[smp * AS * 4];
    float* Mi = &Mi_lds[smp * MSS];

    // ---- own A row into registers
    f16v Ar0, Ar1;
    sfor<4>([&](auto J) {
        constexpr int j = decltype(J)::v;
        float4 v  = lds_a4(As, l, j);
        Ar0[4*j+0] = v.x;  Ar0[4*j+1] = v.y;  Ar0[4*j+2] = v.z;  Ar0[4*j+3] = v.w;
        float4 w4 = lds_a4(As, l, j + 4);
        Ar1[4*j+0] = w4.x; Ar1[4*j+1] = w4.y; Ar1[4*j+2] = w4.z; Ar1[4*j+3] = w4.w;
    });

    // ---- M = A A^T + jitter*I (row l); no duplicated half-group work now
    f16v Mrow, Vrow;
    sfor<16>([&](auto K) {
        constexpr int k = decltype(K)::v;
        float a0 = 0.f, a1 = 0.f, a2 = 0.f, a3 = 0.f;
        sfor<4>([&](auto J) {
            constexpr int j = decltype(J)::v;
            float4 v  = lds_a4(As, k, j);
            a0 += Ar0[4*j+0]*v.x;  a1 += Ar0[4*j+1]*v.y;
            a2 += Ar0[4*j+2]*v.z;  a3 += Ar0[4*j+3]*v.w;
            float4 w4 = lds_a4(As, k, j + 4);
            a0 += Ar1[4*j+0]*w4.x; a1 += Ar1[4*j+1]*w4.y;
            a2 += Ar1[4*j+2]*w4.z; a3 += Ar1[4*j+3]*w4.w;
        });
        Mrow[k] = (a0+a1)+(a2+a3) + ((k == l) ? kJitter : 0.f);
        Vrow[k] = (k == l) ? 1.f : 0.f;
    });

    // ---- TRIANGULAR Gauss-Jordan inverse (SPD -> no pivoting), width-16 shuffles
    sfor<16>([&](auto K) {
        constexpr int k = decltype(K)::v;
        float ip = 1.f / __shfl(Mrow[k], k, 16);
        float f  = (l == k) ? 0.f : Mrow[k] * ip;
        sfor<16>([&](auto J) {
            constexpr int j = decltype(J)::v;
            if constexpr (j > k) {
                float mj = __shfl(Mrow[j], k, 16);
                Mrow[j] = (l == k) ? mj * ip : Mrow[j] - f * mj;
            }
        });
        sfor<16>([&](auto J) {
            constexpr int j = decltype(J)::v;
            if constexpr (j < k) {
                float vj = __shfl(Vrow[j], k, 16);
                Vrow[j] = (l == k) ? vj * ip : Vrow[j] - f * vj;
            }
        });
        Vrow[k] = (l == k) ? ip : -f;
    });

    // ---- w = Minv b (lane holds w[l])
    float w = 0.f;
    {
        float bval = bg[gs * MD + l];
        sfor<16>([&](auto K) {
            constexpr int k = decltype(K)::v;
            w += Vrow[k] * __shfl(bval, k, 16);
        });
    }

    // ---- hand Minv to LDS (all 16 lanes write distinct rows; banks disjoint)
    sfor<4>([&](auto J) {
        constexpr int j = decltype(J)::v;
        *reinterpret_cast<float4*>(&Mi[l * MIS + 4*j]) =
            make_float4(Vrow[4*j+0], Vrow[4*j+1], Vrow[4*j+2], Vrow[4*j+3]);
    });
    asm volatile("s_waitcnt lgkmcnt(0)" ::: "memory");   // same-wave handoff

    // ---- C rows n0,n1 of A^T Minv, fused with q = A^T w (same k, same operands)
    f16v Ca = (f16v)0.0f, Cb = (f16v)0.0f;
    float q0 = 0.f, q1 = 0.f;
    sfor<16>([&](auto K) {
        constexpr int k = decltype(K)::v;
        f2 ak = lds_a2(As, k, n0);                 // (A[k][n0], A[k][n0+1])
        float wm = __shfl(w, k, 16);
        q0 += ak[0] * wm;
        q1 += ak[1] * wm;
        sfor<4>([&](auto J) {
            constexpr int j = decltype(J)::v;
            float4 mv = *reinterpret_cast<const float4*>(&Mi[k * MIS + 4*j]);
            Ca[4*j+0] += ak[0]*mv.x; Ca[4*j+1] += ak[0]*mv.y;
            Ca[4*j+2] += ak[0]*mv.z; Ca[4*j+3] += ak[0]*mv.w;
            Cb[4*j+0] += ak[1]*mv.x; Cb[4*j+1] += ak[1]*mv.y;
            Cb[4*j+2] += ak[1]*mv.z; Cb[4*j+3] += ak[1]*mv.w;
        });
    });

    // ---- P rows n0,n1 = (I - C A)/sigma
    f16v P0a = (f16v)0.0f, P0b = (f16v)0.0f;   // row n0, cols 0-15 / 16-31
    f16v P1a = (f16v)0.0f, P1b = (f16v)0.0f;   // row n1
    sfor<16>([&](auto M) {
        constexpr int m = decltype(M)::v;
        float c0 = Ca[m], c1 = Cb[m];
        sfor<4>([&](auto J) {
            constexpr int j = decltype(J)::v;
            float4 v  = lds_a4(As, m, j);
            P0a[4*j+0] += c0*v.x;  P0a[4*j+1] += c0*v.y;
            P0a[4*j+2] += c0*v.z;  P0a[4*j+3] += c0*v.w;
            P1a[4*j+0] += c1*v.x;  P1a[4*j+1] += c1*v.y;
            P1a[4*j+2] += c1*v.z;  P1a[4*j+3] += c1*v.w;
            float4 w4 = lds_a4(As, m, j + 4);
            P0b[4*j+0] += c0*w4.x; P0b[4*j+1] += c0*w4.y;
            P0b[4*j+2] += c0*w4.z; P0b[4*j+3] += c0*w4.w;
            P1b[4*j+0] += c1*w4.x; P1b[4*j+1] += c1*w4.y;
            P1b[4*j+2] += c1*w4.z; P1b[4*j+3] += c1*w4.w;
        });
    });
    constexpr float is = 1.f / kSigma;
    sfor<16>([&](auto N) {
        constexpr int n = decltype(N)::v;
        P0a[n] = (((n      == n0    ) ? 1.f : 0.f) - P0a[n]) * is;
        P0b[n] = (((n + 16 == n0    ) ? 1.f : 0.f) - P0b[n]) * is;
        P1a[n] = (((n      == n0 + 1) ? 1.f : 0.f) - P1a[n]) * is;
        P1b[n] = (((n + 16 == n0 + 1) ? 1.f : 0.f) - P1b[n]) * is;
    });

    // ---- d = q - P c
    float d0, d1;
    {
        float cv0 = cg[gs * ND + l];
        float cv1 = cg[gs * ND + 16 + l];
        float pc0 = 0.f, pc1 = 0.f;
        sfor<16>([&](auto N) {
            constexpr int n = decltype(N)::v;
            float cn = __shfl(cv0, n, 16);
            pc0 += P0a[n] * cn;
            pc1 += P1a[n] * cn;
        });
        sfor<16>([&](auto N) {
            constexpr int n = decltype(N)::v;
            float cn = __shfl(cv1, n, 16);
            pc0 += P0b[n] * cn;
            pc1 += P1b[n] * cn;
        });
        d0 = q0 - pc0;
        d1 = q1 - pc1;
    }

    // ---- store P (iter layout) and d
    {
        float4* Pout = reinterpret_cast<float4*>(Pws + gs * (ND * ND));
        sfor<8>([&](auto N) {
            constexpr int n = decltype(N)::v;
            Pout[n * 16 + l]       = make_float4(P0a[2*n], P0a[2*n+1], P1a[2*n], P1a[2*n+1]);
            Pout[(n + 8) * 16 + l] = make_float4(P0b[2*n], P0b[2*n+1], P1b[2*n], P1b[2*n+1]);
        });
        f2 dd; dd[0] = d0; dd[1] = d1;
        *reinterpret_cast<f2*>(dws + gs * ND + 2 * l) = dd;
    }
}

// ============================ Kernel B: 100 ADMM iterations ============================
// R8's proven form: 16 lanes/sample, 2 vars/lane, f2 state, f4 P fragments.
__global__ void __launch_bounds__(256)
admm_iter_kernel(const float* __restrict__ Pws, const float* __restrict__ dws,
                 const float* __restrict__ lbg, const float* __restrict__ ubg,
                 float* __restrict__ outg)
{
    __shared__ __align__(16) float S_lds[SPB2 * SS];   // 2304 B

    const int t = threadIdx.x;
    const int lane = t & 63;
    const int l = lane & 15;                       // lane within 16-lane group
    const int smp = (t >> 6) * 4 + (lane >> 4);    // sample within block
    const size_t gs = (size_t)blockIdx.x * SPB2 + smp;
    float* Sb = &S_lds[smp * SS];

    // p_N = (P[2l][2N], P[2l][2N+1], P[2l+1][2N], P[2l+1][2N+1]); coalesced f4 loads
    const f4* Pw = reinterpret_cast<const f4*>(Pws + gs * (ND * ND));
    f4 p0  = Pw[ 0*16 + l], p1  = Pw[ 1*16 + l], p2  = Pw[ 2*16 + l], p3  = Pw[ 3*16 + l];
    f4 p4  = Pw[ 4*16 + l], p5  = Pw[ 5*16 + l], p6  = Pw[ 6*16 + l], p7  = Pw[ 7*16 + l];
    f4 p8  = Pw[ 8*16 + l], p9  = Pw[ 9*16 + l], p10 = Pw[10*16 + l], p11 = Pw[11*16 + l];
    f4 p12 = Pw[12*16 + l], p13 = Pw[13*16 + l], p14 = Pw[14*16 + l], p15 = Pw[15*16 + l];

    f2 dv = *reinterpret_cast<const f2*>(dws + gs * ND + 2 * l);
    f2 lb = *reinterpret_cast<const f2*>(lbg + gs * ND + 2 * l);
    f2 ub = *reinterpret_cast<const f2*>(ubg + gs * ND + 2 * l);
    f2 z  = __builtin_elementwise_min(__builtin_elementwise_max((f2)0.0f, lb), ub);
    f2 u  = (f2)0.0f;
    f2 x  = (f2)0.0f;

    const f4* Sv = reinterpret_cast<const f4*>(Sb);
    for (int it = 0; it < kIters; ++it) {
        *reinterpret_cast<f2*>(&Sb[2 * l]) = z - u;        // rho == 1
        asm volatile("s_waitcnt lgkmcnt(0)" ::: "memory"); // wave-synchronous exchange
        f4 acc0; acc0[0] = dv[0]; acc0[1] = 0.f; acc0[2] = dv[1]; acc0[3] = 0.f;
        f4 acc1 = (f4)0.0f;
#define QP_STEP(q, PA, PB)                                                   \
        {                                                                    \
            f4 S4 = Sv[q];           /* uniform: (s[4q..4q+3]) broadcast */  \
            f4 m0 = __builtin_shufflevector(S4, S4, 0, 1, 0, 1);             \
            f4 m1 = __builtin_shufflevector(S4, S4, 2, 3, 2, 3);             \
            acc0 = __builtin_elementwise_fma(PA, m0, acc0);                  \
            acc1 = __builtin_elementwise_fma(PB, m1, acc1);                  \
        }
        QP_STEP(0, p0,  p1)  QP_STEP(1, p2,  p3)
        QP_STEP(2, p4,  p5)  QP_STEP(3, p6,  p7)
        QP_STEP(4, p8,  p9)  QP_STEP(5, p10, p11)
        QP_STEP(6, p12, p13) QP_STEP(7, p14, p15)
#undef QP_STEP
        f4 s4 = acc0 + acc1;
        x = __builtin_shufflevector(s4, s4, 0, 2) + __builtin_shufflevector(s4, s4, 1, 3);
        f2 tv = x + u;
        z = __builtin_elementwise_min(__builtin_elementwise_max(tv, lb), ub);
        u = tv - z;
    }

    *reinterpret_cast<f2*>(outg + gs * ND + 2 * l) = x;
}

// ==================== Fallback: single kernel (if ws too small) ====================
__global__ void __launch_bounds__(256)
admm_qp_kernel(const float* __restrict__ Ag, const float* __restrict__ bg,
               const float* __restrict__ cg, const float* __restrict__ lbg,
               const float* __restrict__ ubg, float* __restrict__ outg)
{
    __shared__ __align__(16) float A_lds[SPB * AS * 4];
    __shared__ __align__(16) float S_lds[SPB * SS];

    const int t = threadIdx.x;
    {
        const float4* src = reinterpret_cast<const float4*>(Ag) +
                            (size_t)blockIdx.x * (SPB * MD * ND / 4);
        float4* dst = reinterpret_cast<float4*>(A_lds);
        #pragma unroll
        for (int r = 0; r < 4; ++r) {
            int idx = r * 256 + t;
            int smp = idx >> 7;
            int row = (idx >> 3) & 15;
            int j   = idx & 7;
            dst[smp * AS + row * 8 + (j ^ (row & 7))] = src[idx];
        }
    }
    __syncthreads();

    const int lane = t & 63;
    const int l    = lane & 31;
    const int lr   = l & 15;
    const int smp  = (t >> 6) * 2 + (lane >> 5);
    const size_t gs = (size_t)blockIdx.x * SPB + smp;
    const float* As = &A_lds[smp * AS * 4];
    float* Sb = &S_lds[smp * SS];

    f16v Mrow, Vrow;
    sfor<16>([&](auto K) {
        constexpr int k = decltype(K)::v;
        float a0 = 0.f, a1 = 0.f, a2 = 0.f, a3 = 0.f;
        sfor<8>([&](auto J) {
            constexpr int j = decltype(J)::v;
            float4 va = lds_a4(As, lr, j);
            float4 vb = lds_a4(As, k, j);
            a0 += va.x*vb.x; a1 += va.y*vb.y; a2 += va.z*vb.z; a3 += va.w*vb.w;
        });
        Mrow[k] = (a0+a1)+(a2+a3) + ((k == lr) ? kJitter : 0.f);
        Vrow[k] = (k == lr) ? 1.f : 0.f;
    });
    sfor<16>([&](auto K) {
        constexpr int k = decltype(K)::v;
        float ip = 1.f / __shfl(Mrow[k], k, 32);
        float f  = (lr == k) ? 0.f : Mrow[k] * ip;
        sfor<16>([&](auto J) {
            constexpr int j = decltype(J)::v;
            if constexpr (j > k) {
                float mj = __shfl(Mrow[j], k, 32);
                Mrow[j] = (lr == k) ? mj * ip : Mrow[j] - f * mj;
            }
        });
        sfor<16>([&](auto J) {
            constexpr int j = decltype(J)::v;
            if constexpr (j < k) {
                float vj = __shfl(Vrow[j], k, 32);
                Vrow[j] = (lr == k) ? vj * ip : Vrow[j] - f * vj;
            }
        });
        Vrow[k] = (lr == k) ? ip : -f;
    });
    float w = 0.f;
    {
        float bval = bg[gs * MD + lr];
        sfor<16>([&](auto K) {
            constexpr int k = decltype(K)::v;
            w += Vrow[k] * __shfl(bval, k, 32);
        });
    }
    f16v C = (f16v)0.0f;
    sfor<16>([&](auto K) {
        constexpr int k = decltype(K)::v;
        float a = lds_a(As, k, l);
        sfor<16>([&](auto M) {
            constexpr int m = decltype(M)::v;
            C[m] += a * __shfl(Vrow[m], k, 32);
        });
    });
    f16v Pa = (f16v)0.0f, Pb = (f16v)0.0f;
    sfor<16>([&](auto M) {
        constexpr int m = decltype(M)::v;
        float cm = C[m];
        sfor<4>([&](auto J) {
            constexpr int j = decltype(J)::v;
            float4 v  = lds_a4(As, m, j);
            Pa[4*j+0] += cm*v.x;  Pa[4*j+1] += cm*v.y;
            Pa[4*j+2] += cm*v.z;  Pa[4*j+3] += cm*v.w;
            float4 w4 = lds_a4(As, m, j + 4);
            Pb[4*j+0] += cm*w4.x; Pb[4*j+1] += cm*w4.y;
            Pb[4*j+2] += cm*w4.z; Pb[4*j+3] += cm*w4.w;
        });
    });
    constexpr float is = 1.f / kSigma;
    sfor<16>([&](auto N) {
        constexpr int n = decltype(N)::v;
        Pa[n] = (((n      == l) ? 1.f : 0.f) - Pa[n]) * is;
        Pb[n] = (((n + 16 == l) ? 1.f : 0.f) - Pb[n]) * is;
    });
    float d;
    {
        float q = 0.f;
        sfor<16>([&](auto M) {
            constexpr int m = decltype(M)::v;
            q += lds_a(As, m, l) * __shfl(w, m, 32);
        });
        float cval = cg[gs * ND + l];
        float pc0 = 0.f, pc1 = 0.f;
        sfor<16>([&](auto N) {
            constexpr int n = decltype(N)::v;
            pc0 += Pa[n] * __shfl(cval, n,      32);
            pc1 += Pb[n] * __shfl(cval, n + 16, 32);
        });
        d = q - (pc0 + pc1);
    }
    float lb = lbg[gs * ND + l];
    float ub = ubg[gs * ND + l];
    float z  = fminf(fmaxf(0.f, lb), ub);
    float u  = 0.f, x = 0.f;
    for (int it = 0; it < kIters; ++it) {
        Sb[l] = z - u;
        asm volatile("s_waitcnt lgkmcnt(0)" ::: "memory");
        float a0 = d, a1 = 0.f, a2 = 0.f, a3 = 0.f;
        sfor<4>([&](auto K) {
            constexpr int k = decltype(K)::v;
            float4 sA = *reinterpret_cast<const float4*>(&Sb[4*k]);
            float4 sB = *reinterpret_cast<const float4*>(&Sb[4*k + 16]);
            a0 += Pa[4*k+0]*sA.x + Pb[4*k+0]*sB.x;
            a1 += Pa[4*k+1]*sA.y + Pb[4*k+1]*sB.y;
            a2 += Pa[4*k+2]*sA.z + Pb[4*k+2]*sB.z;
            a3 += Pa[4*k+3]*sA.w + Pb[4*k+3]*sB.w;
        });
        x = (a0 + a1) + (a2 + a3);
        float tv = x + u;
        z = fminf(fmaxf(tv, lb), ub);
        u = tv - z;
    }
    outg[gs * ND + l] = x;
}

extern "C" void kernel_launch(void* const* d_in, const int* in_sizes, int n_in,
                              void* d_out, int out_size, void* d_ws, size_t ws_size,
                              hipStream_t stream) {
    const float* A  = (const float*)d_in[0];
    const float* b  = (const float*)d_in[1];
    const float* c  = (const float*)d_in[2];
    const float* lb = (const float*)d_in[3];
    const float* ub = (const float*)d_in[4];
    float* out = (float*)d_out;
    const int B = in_sizes[1] / MD;                       // 32768 samples
    const size_t needP = (size_t)B * ND * ND * sizeof(float);   // 128 MiB
    const size_t needD = (size_t)B * ND * sizeof(float);        // 4 MiB
    if (ws_size >= needP + needD) {
        float* Pws = (float*)d_ws;
        float* dws = Pws + (size_t)B * ND * ND;
        precompute_kernel<<<B / SPA, 128, 0, stream>>>(A, b, c, Pws, dws);
        admm_iter_kernel<<<B / SPB2, 256, 0, stream>>>(Pws, dws, lb, ub, out);
    } else {
        admm_qp_kernel<<<B / SPB, 256, 0, stream>>>(A, b, c, lb, ub, out);
    }
}